// Round 4
// baseline (34.530 us; speedup 1.0000x reference)
//
#include <hip/hip_runtime.h>
#include <hip/hip_bf16.h>
#include <math.h>

// ABMIL gated-attention pooling, one streaming pass.
// a = tanh(x.w1)*sigmoid(x.w2) is bounded in (-1,1) -> softmax needs no max
// subtraction; masked rows contribute exactly 0 (exp(-10000) underflows), so
// we skip them entirely (compacted iteration over ballot mask). out =
// (z@wf^T)/s is linear in z, so each block reduces straight to {pd[4], s}.
// NOTE: per-row score p is wave-uniform (post-butterfly) -> s is uniform;
// do NOT wave_reduce it (R3 bug: 64x overcount of the denominator).

#define NB   4
#define NN   16384
#define DD   1024
#define LL   4
#define NBLK 256            // blocks per bag
#define RPB  (NN / NBLK)    // 64 rows per block
#define RPW  (RPB / 4)      // 16 rows per wave

struct POut { float pd[LL]; float s; float pad[3]; };  // 32 B

__device__ __forceinline__ float wave_reduce(float v) {
    #pragma unroll
    for (int off = 32; off > 0; off >>= 1) v += __shfl_xor(v, off, 64);
    return v;
}

__device__ __forceinline__ float fast_rcp(float x) {
    return __builtin_amdgcn_rcpf(x);
}

// pop lowest set bit index; -1 if empty. m is wave-uniform -> scalar ops.
__device__ __forceinline__ int popnext(unsigned& m) {
    if (m == 0u) return -1;
    const int i = (int)__builtin_ctz(m);
    m &= m - 1u;
    return i;
}

// ---------------------------------------------------------------------------
// Main: grid (NBLK, NB), 256 threads (4 waves). Per wave: ballot 16 validity
// bits, then depth-2 software-pipelined loop over ONLY the valid rows.
// Epilogue: project register-z onto wf (global, L2-hot), tiny LDS combine.
// ---------------------------------------------------------------------------
__global__ __launch_bounds__(256, 4) void abmil_main(
    const float* __restrict__ xs, const void* __restrict__ valid,
    const float* __restrict__ w1, const float* __restrict__ w2,
    const float* __restrict__ wf, POut* __restrict__ parts) {
    const int blk  = blockIdx.x;
    const int bag  = blockIdx.y;
    const int tid  = threadIdx.x;
    const int wave = tid >> 6;
    const int lane = tid & 63;

    __shared__ int   nflag[2];
    __shared__ float comb[4][LL];
    __shared__ float scomb[4];

    // ---- inline dtype detection for `valid` (first 4 KB, L2-hot) ----
    // mode: 0=byte(bool), 1=int32, 2=float32
    if (tid == 0) { nflag[0] = 0; nflag[1] = 0; }
    __syncthreads();
    {
        const uint4 xq = ((const uint4*)valid)[tid];
        const unsigned w[4] = {xq.x, xq.y, xq.z, xq.w};
        int bi = 0, bf = 0;
        #pragma unroll
        for (int j = 0; j < 4; ++j) {
            if (w[j] != 0u && w[j] != 1u) bi = 1;
            if (w[j] != 0u && w[j] != 0x3F800000u) bf = 1;
        }
        if (bi) atomicOr(&nflag[0], 1);
        if (bf) atomicOr(&nflag[1], 1);
    }
    __syncthreads();
    const int mode = (!nflag[0]) ? 1 : ((!nflag[1]) ? 2 : 0);

    // ---- gate weights into registers (16 f32/lane each) ----
    const float4* w1v = (const float4*)w1;
    const float4* w2v = (const float4*)w2;
    float4 w1r[4], w2r[4];
    #pragma unroll
    for (int k = 0; k < 4; ++k) {
        w1r[k] = w1v[k * 64 + lane];
        w2r[k] = w2v[k * 64 + lane];
    }

    // ---- validity bitmask for this wave's 16 rows ----
    const int n0 = blk * RPB + wave * RPW;
    int flag = 0;
    if (lane < RPW) {
        const size_t idx = (size_t)bag * NN + n0 + lane;
        if (mode == 1)      flag = ((const int*)valid)[idx] != 0;
        else if (mode == 2) flag = ((const float*)valid)[idx] != 0.0f;
        else                flag = ((const unsigned char*)valid)[idx] != 0;
    }
    unsigned m = (unsigned)(__ballot(flag) & 0xFFFFull);

    // ---- accumulators ----
    float s = 0.0f;   // wave-uniform (p is uniform post-reduce)
    float4 z[4];
    #pragma unroll
    for (int k = 0; k < 4; ++k) z[k] = make_float4(0.f, 0.f, 0.f, 0.f);

    const float4* xbase = (const float4*)(xs + (size_t)bag * NN * DD);

    auto loadrow = [&](float4 (&xr)[4], int idx) {
        if (idx >= 0) {
            const float4* xp = xbase + (size_t)(n0 + idx) * (DD / 4);
            #pragma unroll
            for (int k = 0; k < 4; ++k) xr[k] = xp[k * 64 + lane];
        }
    };
    auto comprow = [&](const float4 (&xr)[4]) {
        float d1 = 0.f, d2 = 0.f;
        #pragma unroll
        for (int k = 0; k < 4; ++k) {
            d1 += xr[k].x * w1r[k].x + xr[k].y * w1r[k].y +
                  xr[k].z * w1r[k].z + xr[k].w * w1r[k].w;
            d2 += xr[k].x * w2r[k].x + xr[k].y * w2r[k].y +
                  xr[k].z * w2r[k].z + xr[k].w * w2r[k].w;
        }
        #pragma unroll
        for (int off = 32; off > 0; off >>= 1) {
            d1 += __shfl_xor(d1, off, 64);
            d2 += __shfl_xor(d2, off, 64);
        }
        // tanh(d1) = sign(d1)*(1-e)/(1+e), e = exp(-2|d1|)  (overflow-safe)
        const float e  = __expf(-2.0f * fabsf(d1));
        const float t  = copysignf((1.0f - e) * fast_rcp(1.0f + e), d1);
        const float sg = fast_rcp(1.0f + __expf(-d2));
        const float p  = __expf(t * sg);
        s += p;
        #pragma unroll
        for (int k = 0; k < 4; ++k) {
            z[k].x += p * xr[k].x; z[k].y += p * xr[k].y;
            z[k].z += p * xr[k].z; z[k].w += p * xr[k].w;
        }
    };

    // ---- depth-2 pipelined loop over valid rows only ----
    float4 xA[4], xB[4];
    int iA = popnext(m), iB = popnext(m);
    loadrow(xA, iA); loadrow(xB, iB);
    for (;;) {
        if (iA < 0) break;
        comprow(xA); iA = popnext(m); loadrow(xA, iA);
        if (iB < 0) break;
        comprow(xB); iB = popnext(m); loadrow(xB, iB);
    }

    // ---- epilogue: project z onto wf rows (global reads, L2-hot) ----
    const float4* wfv = (const float4*)wf;
    float pl[LL] = {0.f, 0.f, 0.f, 0.f};
    #pragma unroll
    for (int l = 0; l < LL; ++l) {
        #pragma unroll
        for (int k = 0; k < 4; ++k) {
            const float4 wv = wfv[l * 256 + k * 64 + lane];
            pl[l] += z[k].x * wv.x + z[k].y * wv.y +
                     z[k].z * wv.z + z[k].w * wv.w;
        }
    }
    #pragma unroll
    for (int l = 0; l < LL; ++l) pl[l] = wave_reduce(pl[l]);
    if (lane == 0) {
        #pragma unroll
        for (int l = 0; l < LL; ++l) comb[wave][l] = pl[l];
        scomb[wave] = s;   // s is wave-uniform: take it directly, NO reduce
    }
    __syncthreads();

    POut* po = &parts[(size_t)bag * NBLK + blk];
    if (tid < LL)
        po->pd[tid] = comb[0][tid] + comb[1][tid] + comb[2][tid] + comb[3][tid];
    if (tid == LL)
        po->s = scomb[0] + scomb[1] + scomb[2] + scomb[3];
}

// ---------------------------------------------------------------------------
// Finish: 1 block, 256 threads. Wave w owns bag w; 64 lanes sum 256 POuts,
// shuffle-reduce, divide, store 16 floats.
// ---------------------------------------------------------------------------
__global__ __launch_bounds__(256) void abmil_finish(
    const POut* __restrict__ parts, float* __restrict__ out) {
    const int bag  = threadIdx.x >> 6;
    const int lane = threadIdx.x & 63;

    float pd[LL] = {0.f, 0.f, 0.f, 0.f};
    float s = 0.0f;
    #pragma unroll
    for (int j = 0; j < NBLK / 64; ++j) {
        const POut* p = &parts[(size_t)bag * NBLK + j * 64 + lane];
        #pragma unroll
        for (int l = 0; l < LL; ++l) pd[l] += p->pd[l];
        s += p->s;
    }
    #pragma unroll
    for (int l = 0; l < LL; ++l) pd[l] = wave_reduce(pd[l]);
    s = wave_reduce(s);   // here lanes hold DIFFERENT partials: reduce is right
    if (lane == 0) {
        #pragma unroll
        for (int l = 0; l < LL; ++l) out[bag * LL + l] = pd[l] / s;
    }
}

// ---------------------------------------------------------------------------
extern "C" void kernel_launch(void* const* d_in, const int* in_sizes, int n_in,
                              void* d_out, int out_size, void* d_ws, size_t ws_size,
                              hipStream_t stream) {
    const float* xs    = (const float*)d_in[0];
    const void*  valid = d_in[1];
    const float* w1    = (const float*)d_in[2];
    const float* w2    = (const float*)d_in[3];
    const float* wf    = (const float*)d_in[4];
    float* out = (float*)d_out;

    POut* parts = (POut*)d_ws;   // NB*NBLK*32 B = 32 KB << ws_size

    dim3 g0(NBLK, NB);
    abmil_main<<<g0, 256, 0, stream>>>(xs, valid, w1, w2, wf, parts);
    abmil_finish<<<1, 256, 0, stream>>>(parts, out);
}